// Round 6
// baseline (167.157 us; speedup 1.0000x reference)
//
#include <hip/hip_runtime.h>
#include <stdint.h>

typedef __bf16 bf16;
typedef __bf16 bf16x2 __attribute__((ext_vector_type(2)));
typedef __bf16 bf16x4 __attribute__((ext_vector_type(4)));
typedef __bf16 bf16x8 __attribute__((ext_vector_type(8)));
typedef float f32x4 __attribute__((ext_vector_type(4)));

#define D_MODEL 1024
#define NHEADS 16
#define HEADDIM 64
#define SEQ 2048
#define NBATCH 2

__device__ __forceinline__ void async_load16(const void* g, void* l) {
  __builtin_amdgcn_global_load_lds(
      (__attribute__((address_space(1))) void*)g,
      (__attribute__((address_space(3))) void*)l, 16, 0, 0);
}

__device__ __forceinline__ float fexp2(float x) {
#if __has_builtin(__builtin_amdgcn_exp2f)
  return __builtin_amdgcn_exp2f(x);
#else
  return exp2f(x);
#endif
}

// ---------------- LayerNorm: fp32 x -> bf16 y ----------------
__global__ __launch_bounds__(256)
void ln_kernel(const float* __restrict__ x, const float* __restrict__ w,
               const float* __restrict__ b, bf16* __restrict__ y) {
  int row = blockIdx.x;
  int t = threadIdx.x;
  const float4 v = ((const float4*)(x + (size_t)row * D_MODEL))[t];
  float s = v.x + v.y + v.z + v.w;
  float sq = v.x * v.x + v.y * v.y + v.z * v.z + v.w * v.w;
#pragma unroll
  for (int d = 1; d < 64; d <<= 1) {
    s += __shfl_xor(s, d);
    sq += __shfl_xor(sq, d);
  }
  __shared__ float ps[4], pq[4];
  if ((t & 63) == 0) { ps[t >> 6] = s; pq[t >> 6] = sq; }
  __syncthreads();
  s = ps[0] + ps[1] + ps[2] + ps[3];
  sq = pq[0] + pq[1] + pq[2] + pq[3];
  float mean = s * (1.0f / D_MODEL);
  float var = sq * (1.0f / D_MODEL) - mean * mean;
  float rstd = rsqrtf(var + 1e-5f);
  float4 wv = ((const float4*)w)[t];
  float4 bv = ((const float4*)b)[t];
  bf16x4 o;
  o[0] = (bf16)((v.x - mean) * rstd * wv.x + bv.x);
  o[1] = (bf16)((v.y - mean) * rstd * wv.y + bv.y);
  o[2] = (bf16)((v.z - mean) * rstd * wv.z + bv.z);
  o[3] = (bf16)((v.w - mean) * rstd * wv.w + bv.w);
  ((bf16x4*)(y + (size_t)row * D_MODEL))[t] = o;
}

// ------------- transpose + cast: src fp32 [R][C] -> dst bf16 [C][R] -------------
__global__ __launch_bounds__(256)
void transpose_cast(const float* __restrict__ src, bf16* __restrict__ dst,
                    int src_ld, int dst_ld, int tiles_c,
                    long src_bstride, long dst_bstride) {
  __shared__ float tile[64][65];
  int tr = blockIdx.x / tiles_c, tc = blockIdx.x % tiles_c;
  const float* s = src + (long)blockIdx.y * src_bstride + (size_t)(tr * 64) * src_ld + (size_t)tc * 64;
  bf16* d = dst + (long)blockIdx.y * dst_bstride + (size_t)(tc * 64) * dst_ld + (size_t)tr * 64;
  int t = threadIdx.x;
  int rr = t >> 4;
  int cc = (t & 15) << 2;
#pragma unroll
  for (int i = 0; i < 4; ++i) {
    float4 v = *(const float4*)&s[(size_t)(rr + i * 16) * src_ld + cc];
    tile[rr + i * 16][cc + 0] = v.x;
    tile[rr + i * 16][cc + 1] = v.y;
    tile[rr + i * 16][cc + 2] = v.z;
    tile[rr + i * 16][cc + 3] = v.w;
  }
  __syncthreads();
#pragma unroll
  for (int i = 0; i < 4; ++i) {
    int drow = rr + i * 16;
    bf16x4 o;
    o[0] = (bf16)tile[cc + 0][drow];
    o[1] = (bf16)tile[cc + 1][drow];
    o[2] = (bf16)tile[cc + 2][drow];
    o[3] = (bf16)tile[cc + 3][drow];
    *(bf16x4*)&d[(size_t)drow * dst_ld + cc] = o;
  }
}

// ------------- GEMM: C[M][N] = A[M][K=1024] * Bt[N][K=1024]^T -------------
// Swizzled dbuf staging (proven R5). Templated on BM (128: 2x2 waves of
// 64x64; 64: 1x4 waves of 64x32). BN always 128.
// MODE 0: fused QKV. N=3072: cols 0..1023 -> q[b][h][s][e] (p0),
//         1024..2047 -> k (p1), 2048..3071 -> v^T[b][h][e][s] (p2, bf16x4).
// MODE 2: fp32 out = acc + x (p0=out, p1=x)
template <int MODE, int BM>
__global__ __launch_bounds__(256)
void gemm_bt(const bf16* __restrict__ A, const bf16* __restrict__ Bt,
             int ntn, void* __restrict__ p0, void* __restrict__ p1,
             void* __restrict__ p2) {
  constexpr int NWC = (BM == 128) ? 2 : 4;  // wave cols
  constexpr int NJ = 8 / NWC;               // j-tiles per wave
  __shared__ __align__(16) bf16 As[2][BM * 64];
  __shared__ __align__(16) bf16 Bs[2][128 * 64];
  int cpx = gridDim.x >> 3;
  int wg = (blockIdx.x & 7) * cpx + (blockIdx.x >> 3);
  int bm = wg / ntn;
  int bn = wg % ntn;
  int t = threadIdx.x;
  int w = t >> 6, l = t & 63;
  int lg = l >> 4, lo = l & 15;
  int wr = w / NWC, wc = w % NWC;
  const bf16* Ab = A + (size_t)bm * BM * 1024;
  const bf16* Bb = Bt + (size_t)bn * 128 * 1024;
  f32x4 acc[4][NJ];
#pragma unroll
  for (int i = 0; i < 4; ++i)
#pragma unroll
    for (int j = 0; j < NJ; ++j) acc[i][j] = (f32x4){0.f, 0.f, 0.f, 0.f};

  auto stage = [&](int bufi, int k0) {
#pragma unroll
    for (int it = 0; it < BM / 32; ++it) {
      int flat = it * 2048 + t * 8;
      int row = flat >> 6, sc = ((flat & 63) >> 3) ^ (row & 7);
      async_load16(Ab + (size_t)row * 1024 + k0 + sc * 8, &As[bufi][it * 2048 + w * 512]);
    }
#pragma unroll
    for (int it = 0; it < 4; ++it) {
      int flat = it * 2048 + t * 8;
      int row = flat >> 6, sc = ((flat & 63) >> 3) ^ (row & 7);
      async_load16(Bb + (size_t)row * 1024 + k0 + sc * 8, &Bs[bufi][it * 2048 + w * 512]);
    }
  };

  stage(0, 0);
  __syncthreads();
  int buf = 0;
  for (int k0 = 0; k0 < 1024; k0 += 64) {
    if (k0 + 64 < 1024) stage(buf ^ 1, k0 + 64);  // async prefetch over compute
#pragma unroll
    for (int kk = 0; kk < 2; ++kk) {
      bf16x8 af[4], bfr[NJ];
#pragma unroll
      for (int i = 0; i < 4; ++i) {
        int row = wr * 64 + i * 16 + lo;
        af[i] = *(const bf16x8*)&As[buf][row * 64 + (((4 * kk + lg) ^ (lo & 7)) * 8)];
      }
#pragma unroll
      for (int j = 0; j < NJ; ++j) {
        int row = wc * (NJ * 16) + j * 16 + lo;
        bfr[j] = *(const bf16x8*)&Bs[buf][row * 64 + (((4 * kk + lg) ^ (lo & 7)) * 8)];
      }
#pragma unroll
      for (int i = 0; i < 4; ++i)
#pragma unroll
        for (int j = 0; j < NJ; ++j)
          acc[i][j] = __builtin_amdgcn_mfma_f32_16x16x32_bf16(af[i], bfr[j], acc[i][j], 0, 0, 0);
    }
    __syncthreads();
    buf ^= 1;
  }

  int mbase = bm * BM + wr * 64;
  int nbase = bn * 128 + wc * (NJ * 16);
#pragma unroll
  for (int i = 0; i < 4; ++i) {
#pragma unroll
    for (int j = 0; j < NJ; ++j) {
      int row0 = mbase + i * 16 + lg * 4;
      int col = nbase + j * 16 + lo;
      if (MODE == 0) {
        if (col < 2048) {  // q or k, [b][h][s][e]
          bf16* dst = (bf16*)(col < 1024 ? p0 : p1);
          int c = col & 1023;
          int h = c >> 6, e = c & 63;
#pragma unroll
          for (int r = 0; r < 4; ++r) {
            int row = row0 + r;
            dst[((((size_t)(row >> 11) * NHEADS + h) * SEQ) + (row & 2047)) * HEADDIM + e] =
                (bf16)acc[i][j][r];
          }
        } else {  // v^T [b][h][e][s], packed 4 consecutive s
          int c = col - 2048;
          int h = c >> 6, e = c & 63;
          int b_ = row0 >> 11, s_ = row0 & 2047;
          bf16x4 pk;
          pk[0] = (bf16)acc[i][j][0]; pk[1] = (bf16)acc[i][j][1];
          pk[2] = (bf16)acc[i][j][2]; pk[3] = (bf16)acc[i][j][3];
          *(bf16x4*)&((bf16*)p2)[(((size_t)b_ * NHEADS + h) * HEADDIM + e) * SEQ + s_] = pk;
        }
      } else {
#pragma unroll
        for (int r = 0; r < 4; ++r) {
          int row = row0 + r;
          float xr = ((const float*)p1)[(size_t)row * 1024 + col];
          ((float*)p0)[(size_t)row * 1024 + col] = acc[i][j][r] + xr;
        }
      }
    }
  }
}

// ------------- causal flash attention v6 -------------
// 512 threads (8 waves), 128 Q-rows per block: one K/V staging stream feeds
// 8 waves (staging & barriers halved vs v5). Waves fully past the diagonal
// skip compute (uniform branch) but participate in staging/barriers.
// XCD-grouped decode (16 blocks per bh on one XCD), heavy-first order.
// Per-wave math identical to proven v5.
__global__ __launch_bounds__(512)
void attn_kernel(const bf16* __restrict__ q, const bf16* __restrict__ k,
                 const bf16* __restrict__ vt, bf16* __restrict__ attn) {
  __shared__ __align__(16) bf16 Ks[2][64 * 64];
  __shared__ __align__(16) bf16 Vs[2][64 * 64];
  __shared__ __align__(16) bf16 P[8][16 * 64];
  const float C2 = 0.125f * 1.44269504f;
  int i = blockIdx.x;
  int slot = i >> 3;
  int bh = (i & 7) + 8 * (slot >> 4);  // round-robin dispatch i -> XCD i%8
  int tb = 15 - (slot & 15);           // heavy blocks first
  int b = bh >> 4, h = bh & 15;
  int t = threadIdx.x, w = t >> 6, l = t & 63;
  int lg = l >> 4, lo = l & 15;
  const bf16* qp = q + (size_t)bh * SEQ * HEADDIM;
  const bf16* kp = k + (size_t)bh * SEQ * HEADDIM;
  const bf16* vp = vt + (size_t)bh * HEADDIM * SEQ;
  int q0 = tb * 128 + w * 16;
  int cd = q0 >> 6;        // this wave's diagonal chunk
  int nc = 2 * tb + 2;     // chunks staged by the block

  bf16x8 qf0 = *(const bf16x8*)&qp[(size_t)(q0 + lo) * HEADDIM + 8 * lg];
  bf16x8 qf1 = *(const bf16x8*)&qp[(size_t)(q0 + lo) * HEADDIM + 32 + 8 * lg];

  // 512 threads: 1 load each for K and V per chunk (64x64 bf16 tiles)
  auto stage = [&](int bufi, int kv0) {
    int row = t >> 3, c16 = t & 7;
    int sc = c16 ^ (row & 7);
    async_load16(kp + (size_t)(kv0 + row) * HEADDIM + sc * 8, &Ks[bufi][(t >> 6) * 512 + (t & 63) * 8]);
    async_load16(vp + (size_t)row * SEQ + kv0 + sc * 8, &Vs[bufi][(t >> 6) * 512 + (t & 63) * 8]);
  };

  f32x4 o[4];
#pragma unroll
  for (int nt = 0; nt < 4; ++nt) o[nt] = (f32x4){0.f, 0.f, 0.f, 0.f};
  float m = -1e30f, lsum = 0.f;       // per-lane, q-row = q0 + lo
  int diag_rhs = (w & 3) * 16 + lo;   // kv-local bound on the diagonal chunk

  int buf = 0;
  stage(0, 0);
  __syncthreads();

  for (int c = 0; c < nc; ++c) {
    if (c + 1 < nc) stage(buf ^ 1, (c + 1) * 64);  // async prefetch

    if (c <= cd) {  // uniform per-wave: skip fully-masked chunks
      // S^T = K * Q^T : C[kv][q], lane owns q = lo, kv = 16*nt + 4*lg + r
      f32x4 s[4];
      __builtin_amdgcn_s_setprio(1);
#pragma unroll
      for (int nt = 0; nt < 4; ++nt) {
        s[nt] = (f32x4){0.f, 0.f, 0.f, 0.f};
        int krow = nt * 16 + lo;
        bf16x8 kf0 = *(const bf16x8*)&Ks[buf][krow * 64 + ((lg ^ (lo & 7)) * 8)];
        bf16x8 kf1 = *(const bf16x8*)&Ks[buf][krow * 64 + (((4 + lg) ^ (lo & 7)) * 8)];
        s[nt] = __builtin_amdgcn_mfma_f32_16x16x32_bf16(kf0, qf0, s[nt], 0, 0, 0);
        s[nt] = __builtin_amdgcn_mfma_f32_16x16x32_bf16(kf1, qf1, s[nt], 0, 0, 0);
      }
      __builtin_amdgcn_s_setprio(0);

      if (c == cd) {  // causal mask, diagonal chunk only
#pragma unroll
        for (int nt = 0; nt < 4; ++nt)
#pragma unroll
          for (int r = 0; r < 4; ++r)
            s[nt][r] = (16 * nt + 4 * lg + r <= diag_rhs) ? s[nt][r] : -1e30f;
      }

      // in-lane max tree (16 values) + 2 cross-group shuffles
      float mx0 = fmaxf(fmaxf(s[0][0], s[0][1]), fmaxf(s[0][2], s[0][3]));
      float mx1 = fmaxf(fmaxf(s[1][0], s[1][1]), fmaxf(s[1][2], s[1][3]));
      float mx2 = fmaxf(fmaxf(s[2][0], s[2][1]), fmaxf(s[2][2], s[2][3]));
      float mx3 = fmaxf(fmaxf(s[3][0], s[3][1]), fmaxf(s[3][2], s[3][3]));
      float pmax = fmaxf(fmaxf(mx0, mx1), fmaxf(mx2, mx3));
      pmax = fmaxf(pmax, __shfl_xor(pmax, 16));
      pmax = fmaxf(pmax, __shfl_xor(pmax, 32));

      // defer-max rescale (threshold 40 raw = 5 nats)
      if (__any(pmax > m + 40.0f)) {
        float mn = fmaxf(m, pmax);
        float alpha = fexp2((m - mn) * C2);
        m = mn;
        lsum *= alpha;
#pragma unroll
        for (int r = 0; r < 4; ++r) {
          float ar = __shfl(alpha, (l & 48) | (4 * lg + r));
          o[0][r] *= ar; o[1][r] *= ar; o[2][r] *= ar; o[3][r] *= ar;
        }
      }

      float mC = m * C2;
      float p[4][4];
      float psum[4];
#pragma unroll
      for (int nt = 0; nt < 4; ++nt) {
        psum[nt] = 0.f;
#pragma unroll
        for (int r = 0; r < 4; ++r) {
          float e = fexp2(fmaf(s[nt][r], C2, -mC));
          p[nt][r] = e;
          psum[nt] += e;
        }
      }
      float pst = (psum[0] + psum[1]) + (psum[2] + psum[3]);
      pst += __shfl_xor(pst, 16);
      pst += __shfl_xor(pst, 32);
      lsum += pst;

      // P[q=lo][kv] -> per-wave LDS (swizzled), packed b32 writes
#pragma unroll
      for (int nt = 0; nt < 4; ++nt) {
        int chunk = (2 * nt + (lg >> 1)) ^ (lo & 7);
        int base = lo * 64 + chunk * 8 + 4 * (lg & 1);
        bf16x2 w0, w1;
        w0[0] = (bf16)p[nt][0]; w0[1] = (bf16)p[nt][1];
        w1[0] = (bf16)p[nt][2]; w1[1] = (bf16)p[nt][3];
        *(bf16x2*)&P[w][base] = w0;
        *(bf16x2*)&P[w][base + 2] = w1;
      }
      bf16x8 pf0 = *(const bf16x8*)&P[w][lo * 64 + ((lg ^ (lo & 7)) * 8)];
      bf16x8 pf1 = *(const bf16x8*)&P[w][lo * 64 + (((4 + lg) ^ (lo & 7)) * 8)];

      __builtin_amdgcn_s_setprio(1);
#pragma unroll
      for (int nt = 0; nt < 4; ++nt) {
        int vrow = nt * 16 + lo;
        bf16x8 vf0 = *(const bf16x8*)&Vs[buf][vrow * 64 + ((lg ^ (lo & 7)) * 8)];
        bf16x8 vf1 = *(const bf16x8*)&Vs[buf][vrow * 64 + (((4 + lg) ^ (lo & 7)) * 8)];
        o[nt] = __builtin_amdgcn_mfma_f32_16x16x32_bf16(pf0, vf0, o[nt], 0, 0, 0);
        o[nt] = __builtin_amdgcn_mfma_f32_16x16x32_bf16(pf1, vf1, o[nt], 0, 0, 0);
      }
      __builtin_amdgcn_s_setprio(0);
    }

    __syncthreads();  // drains prefetch + all waves done with buf
    buf ^= 1;
  }

#pragma unroll
  for (int r = 0; r < 4; ++r) {
    float ls = __shfl(lsum, (l & 48) | (4 * lg + r));
    float inv = 1.0f / ls;
    int qrow = q0 + 4 * lg + r;
#pragma unroll
    for (int nt = 0; nt < 4; ++nt)
      attn[((size_t)b * SEQ + qrow) * D_MODEL + h * HEADDIM + nt * 16 + lo] =
          (bf16)(o[nt][r] * inv);
  }
}

extern "C" void kernel_launch(void* const* d_in, const int* in_sizes, int n_in,
                              void* d_out, int out_size, void* d_ws, size_t ws_size,
                              hipStream_t stream) {
  const float* x = (const float*)d_in[0];
  const float* ln_w = (const float*)d_in[1];
  const float* ln_b = (const float*)d_in[2];
  const float* wq = (const float*)d_in[3];
  const float* wk = (const float*)d_in[4];
  const float* wv = (const float*)d_in[5];
  const float* wo = (const float*)d_in[6];
  float* out = (float*)d_out;
  char* ws = (char*)d_ws;

  bf16* y     = (bf16*)(ws);                     // 8 MB
  bf16* WqkvT = (bf16*)(ws + (8u << 20));        // 6 MB  [3072][1024]
  bf16* woT   = (bf16*)(ws + (14u << 20));       // 2 MB  [1024][1024]
  bf16* qb    = (bf16*)(ws + (16u << 20));       // 8 MB  [b][h][s][e]
  bf16* kb    = (bf16*)(ws + (24u << 20));       // 8 MB  [b][h][s][e]
  bf16* vtb   = (bf16*)(ws + (32u << 20));       // 8 MB  [b][h][e][s]
  bf16* attnb = (bf16*)(ws + (40u << 20));       // 8 MB  [b*s][h*e]

  // LayerNorm
  ln_kernel<<<NBATCH * SEQ, 256, 0, stream>>>(x, ln_w, ln_b, y);

  // weights -> k-contiguous bf16 transposes
  transpose_cast<<<dim3(16, 16), 256, 0, stream>>>(wq, WqkvT,                64, 1024, 1, 65536, 65536);
  transpose_cast<<<dim3(16, 16), 256, 0, stream>>>(wk, WqkvT + (1u << 20),   64, 1024, 1, 65536, 65536);
  transpose_cast<<<dim3(16, 16), 256, 0, stream>>>(wv, WqkvT + (2u << 20),   64, 1024, 1, 65536, 65536);
  transpose_cast<<<dim3(256, 1), 256, 0, stream>>>(wo, woT,                1024, 1024, 16, 0, 0);

  // fused QKV projection: [4096,1024] x [3072,1024]^T, 3-way output decode
  gemm_bt<0, 128><<<32 * 24, 256, 0, stream>>>(y, WqkvT, 24, qb, kb, vtb);

  // causal flash attention (1024 blocks x 512 thr, XCD-grouped)
  attn_kernel<<<dim3(1024), 512, 0, stream>>>(qb, kb, vtb, attnb);

  // output projection + residual: [4096,1024] x [1024,1024]^T + x, 64x128 tiles
  gemm_bt<2, 64><<<64 * 8, 256, 0, stream>>>(attnb, woT, 8, out, (void*)x, nullptr);
}

// Round 7
// 133.940 us; speedup vs baseline: 1.2480x; 1.2480x over previous
//
#include <hip/hip_runtime.h>
#include <stdint.h>

typedef __bf16 bf16;
typedef __bf16 bf16x2 __attribute__((ext_vector_type(2)));
typedef __bf16 bf16x4 __attribute__((ext_vector_type(4)));
typedef __bf16 bf16x8 __attribute__((ext_vector_type(8)));
typedef float f32x4 __attribute__((ext_vector_type(4)));

#define D_MODEL 1024
#define NHEADS 16
#define HEADDIM 64
#define SEQ 2048
#define NBATCH 2

__device__ __forceinline__ void async_load16(const void* g, void* l) {
  __builtin_amdgcn_global_load_lds(
      (__attribute__((address_space(1))) void*)g,
      (__attribute__((address_space(3))) void*)l, 16, 0, 0);
}

__device__ __forceinline__ float fexp2(float x) {
#if __has_builtin(__builtin_amdgcn_exp2f)
  return __builtin_amdgcn_exp2f(x);
#else
  return exp2f(x);
#endif
}

// ---------------- LayerNorm: fp32 x -> bf16 y ----------------
__global__ __launch_bounds__(256)
void ln_kernel(const float* __restrict__ x, const float* __restrict__ w,
               const float* __restrict__ b, bf16* __restrict__ y) {
  int row = blockIdx.x;
  int t = threadIdx.x;
  const float4 v = ((const float4*)(x + (size_t)row * D_MODEL))[t];
  float s = v.x + v.y + v.z + v.w;
  float sq = v.x * v.x + v.y * v.y + v.z * v.z + v.w * v.w;
#pragma unroll
  for (int d = 1; d < 64; d <<= 1) {
    s += __shfl_xor(s, d);
    sq += __shfl_xor(sq, d);
  }
  __shared__ float ps[4], pq[4];
  if ((t & 63) == 0) { ps[t >> 6] = s; pq[t >> 6] = sq; }
  __syncthreads();
  s = ps[0] + ps[1] + ps[2] + ps[3];
  sq = pq[0] + pq[1] + pq[2] + pq[3];
  float mean = s * (1.0f / D_MODEL);
  float var = sq * (1.0f / D_MODEL) - mean * mean;
  float rstd = rsqrtf(var + 1e-5f);
  float4 wv = ((const float4*)w)[t];
  float4 bv = ((const float4*)b)[t];
  bf16x4 o;
  o[0] = (bf16)((v.x - mean) * rstd * wv.x + bv.x);
  o[1] = (bf16)((v.y - mean) * rstd * wv.y + bv.y);
  o[2] = (bf16)((v.z - mean) * rstd * wv.z + bv.z);
  o[3] = (bf16)((v.w - mean) * rstd * wv.w + bv.w);
  ((bf16x4*)(y + (size_t)row * D_MODEL))[t] = o;
}

// ------------- transpose + cast: src fp32 [R][C] -> dst bf16 [C][R] -------------
__global__ __launch_bounds__(256)
void transpose_cast(const float* __restrict__ src, bf16* __restrict__ dst,
                    int src_ld, int dst_ld, int tiles_c,
                    long src_bstride, long dst_bstride) {
  __shared__ float tile[64][65];
  int tr = blockIdx.x / tiles_c, tc = blockIdx.x % tiles_c;
  const float* s = src + (long)blockIdx.y * src_bstride + (size_t)(tr * 64) * src_ld + (size_t)tc * 64;
  bf16* d = dst + (long)blockIdx.y * dst_bstride + (size_t)(tc * 64) * dst_ld + (size_t)tr * 64;
  int t = threadIdx.x;
  int rr = t >> 4;
  int cc = (t & 15) << 2;
#pragma unroll
  for (int i = 0; i < 4; ++i) {
    float4 v = *(const float4*)&s[(size_t)(rr + i * 16) * src_ld + cc];
    tile[rr + i * 16][cc + 0] = v.x;
    tile[rr + i * 16][cc + 1] = v.y;
    tile[rr + i * 16][cc + 2] = v.z;
    tile[rr + i * 16][cc + 3] = v.w;
  }
  __syncthreads();
#pragma unroll
  for (int i = 0; i < 4; ++i) {
    int drow = rr + i * 16;
    bf16x4 o;
    o[0] = (bf16)tile[cc + 0][drow];
    o[1] = (bf16)tile[cc + 1][drow];
    o[2] = (bf16)tile[cc + 2][drow];
    o[3] = (bf16)tile[cc + 3][drow];
    *(bf16x4*)&d[(size_t)drow * dst_ld + cc] = o;
  }
}

// ------------- GEMM: C[M][N] = A[M][K=1024] * Bt[N][K=1024]^T -------------
// Swizzled dbuf staging. Templated on BM (128: 2x2 waves of 64x64; 64: 1x4
// waves of 64x32). BN always 128.
// MODE 0: fused QKV. N=3072: cols 0..1023 -> q[b][h][s][e] (p0),
//         1024..2047 -> k (p1), 2048..3071 -> v^T[b][h][e][s] (p2, bf16x4).
// MODE 2: fp32 out = acc + x (p0=out, p1=x)
template <int MODE, int BM>
__global__ __launch_bounds__(256)
void gemm_bt(const bf16* __restrict__ A, const bf16* __restrict__ Bt,
             int ntn, void* __restrict__ p0, void* __restrict__ p1,
             void* __restrict__ p2) {
  constexpr int NWC = (BM == 128) ? 2 : 4;  // wave cols
  constexpr int NJ = 8 / NWC;               // j-tiles per wave
  __shared__ __align__(16) bf16 As[2][BM * 64];
  __shared__ __align__(16) bf16 Bs[2][128 * 64];
  int cpx = gridDim.x >> 3;
  int wg = (blockIdx.x & 7) * cpx + (blockIdx.x >> 3);
  int bm = wg / ntn;
  int bn = wg % ntn;
  int t = threadIdx.x;
  int w = t >> 6, l = t & 63;
  int lg = l >> 4, lo = l & 15;
  int wr = w / NWC, wc = w % NWC;
  const bf16* Ab = A + (size_t)bm * BM * 1024;
  const bf16* Bb = Bt + (size_t)bn * 128 * 1024;
  f32x4 acc[4][NJ];
#pragma unroll
  for (int i = 0; i < 4; ++i)
#pragma unroll
    for (int j = 0; j < NJ; ++j) acc[i][j] = (f32x4){0.f, 0.f, 0.f, 0.f};

  auto stage = [&](int bufi, int k0) {
#pragma unroll
    for (int it = 0; it < BM / 32; ++it) {
      int flat = it * 2048 + t * 8;
      int row = flat >> 6, sc = ((flat & 63) >> 3) ^ (row & 7);
      async_load16(Ab + (size_t)row * 1024 + k0 + sc * 8, &As[bufi][it * 2048 + w * 512]);
    }
#pragma unroll
    for (int it = 0; it < 4; ++it) {
      int flat = it * 2048 + t * 8;
      int row = flat >> 6, sc = ((flat & 63) >> 3) ^ (row & 7);
      async_load16(Bb + (size_t)row * 1024 + k0 + sc * 8, &Bs[bufi][it * 2048 + w * 512]);
    }
  };

  stage(0, 0);
  __syncthreads();
  int buf = 0;
  for (int k0 = 0; k0 < 1024; k0 += 64) {
    if (k0 + 64 < 1024) stage(buf ^ 1, k0 + 64);  // async prefetch over compute
#pragma unroll
    for (int kk = 0; kk < 2; ++kk) {
      bf16x8 af[4], bfr[NJ];
#pragma unroll
      for (int i = 0; i < 4; ++i) {
        int row = wr * 64 + i * 16 + lo;
        af[i] = *(const bf16x8*)&As[buf][row * 64 + (((4 * kk + lg) ^ (lo & 7)) * 8)];
      }
#pragma unroll
      for (int j = 0; j < NJ; ++j) {
        int row = wc * (NJ * 16) + j * 16 + lo;
        bfr[j] = *(const bf16x8*)&Bs[buf][row * 64 + (((4 * kk + lg) ^ (lo & 7)) * 8)];
      }
#pragma unroll
      for (int i = 0; i < 4; ++i)
#pragma unroll
        for (int j = 0; j < NJ; ++j)
          acc[i][j] = __builtin_amdgcn_mfma_f32_16x16x32_bf16(af[i], bfr[j], acc[i][j], 0, 0, 0);
    }
    __syncthreads();
    buf ^= 1;
  }

  int mbase = bm * BM + wr * 64;
  int nbase = bn * 128 + wc * (NJ * 16);
#pragma unroll
  for (int i = 0; i < 4; ++i) {
#pragma unroll
    for (int j = 0; j < NJ; ++j) {
      int row0 = mbase + i * 16 + lg * 4;
      int col = nbase + j * 16 + lo;
      if (MODE == 0) {
        if (col < 2048) {  // q or k, [b][h][s][e]
          bf16* dst = (bf16*)(col < 1024 ? p0 : p1);
          int c = col & 1023;
          int h = c >> 6, e = c & 63;
#pragma unroll
          for (int r = 0; r < 4; ++r) {
            int row = row0 + r;
            dst[((((size_t)(row >> 11) * NHEADS + h) * SEQ) + (row & 2047)) * HEADDIM + e] =
                (bf16)acc[i][j][r];
          }
        } else {  // v^T [b][h][e][s], packed 4 consecutive s
          int c = col - 2048;
          int h = c >> 6, e = c & 63;
          int b_ = row0 >> 11, s_ = row0 & 2047;
          bf16x4 pk;
          pk[0] = (bf16)acc[i][j][0]; pk[1] = (bf16)acc[i][j][1];
          pk[2] = (bf16)acc[i][j][2]; pk[3] = (bf16)acc[i][j][3];
          *(bf16x4*)&((bf16*)p2)[(((size_t)b_ * NHEADS + h) * HEADDIM + e) * SEQ + s_] = pk;
        }
      } else {
#pragma unroll
        for (int r = 0; r < 4; ++r) {
          int row = row0 + r;
          float xr = ((const float*)p1)[(size_t)row * 1024 + col];
          ((float*)p0)[(size_t)row * 1024 + col] = acc[i][j][r] + xr;
        }
      }
    }
  }
}

// ------------- causal flash attention v7 -------------
// v6 structure (8 waves, 128 Q-rows/block, shared K/V staging stream) with
// the grid bug fixed: 512 blocks (32 bh x 16 tiles), decode keeps all 16
// blocks of a bh on one XCD (i&7 == bh&7). Per-wave math = proven v5.
__global__ __launch_bounds__(512)
void attn_kernel(const bf16* __restrict__ q, const bf16* __restrict__ k,
                 const bf16* __restrict__ vt, bf16* __restrict__ attn) {
  __shared__ __align__(16) bf16 Ks[2][64 * 64];
  __shared__ __align__(16) bf16 Vs[2][64 * 64];
  __shared__ __align__(16) bf16 P[8][16 * 64];
  const float C2 = 0.125f * 1.44269504f;
  int i = blockIdx.x;          // 0..511
  int slot = i >> 3;           // 0..63
  int bh = (i & 7) + 8 * (slot >> 4);  // 0..31; i&7 == bh&7 -> one XCD per bh
  int tb = 15 - (slot & 15);   // heavy blocks first
  int b = bh >> 4, h = bh & 15;
  int t = threadIdx.x, w = t >> 6, l = t & 63;
  int lg = l >> 4, lo = l & 15;
  const bf16* qp = q + (size_t)bh * SEQ * HEADDIM;
  const bf16* kp = k + (size_t)bh * SEQ * HEADDIM;
  const bf16* vp = vt + (size_t)bh * HEADDIM * SEQ;
  int q0 = tb * 128 + w * 16;
  int cd = q0 >> 6;        // this wave's diagonal chunk
  int nc = 2 * tb + 2;     // chunks staged by the block

  bf16x8 qf0 = *(const bf16x8*)&qp[(size_t)(q0 + lo) * HEADDIM + 8 * lg];
  bf16x8 qf1 = *(const bf16x8*)&qp[(size_t)(q0 + lo) * HEADDIM + 32 + 8 * lg];

  // 512 threads: 1 load each for K and V per chunk (64x64 bf16 tiles)
  auto stage = [&](int bufi, int kv0) {
    int row = t >> 3, c16 = t & 7;
    int sc = c16 ^ (row & 7);
    async_load16(kp + (size_t)(kv0 + row) * HEADDIM + sc * 8, &Ks[bufi][(t >> 6) * 512 + (t & 63) * 8]);
    async_load16(vp + (size_t)row * SEQ + kv0 + sc * 8, &Vs[bufi][(t >> 6) * 512 + (t & 63) * 8]);
  };

  f32x4 o[4];
#pragma unroll
  for (int nt = 0; nt < 4; ++nt) o[nt] = (f32x4){0.f, 0.f, 0.f, 0.f};
  float m = -1e30f, lsum = 0.f;       // per-lane, q-row = q0 + lo
  int diag_rhs = (w & 3) * 16 + lo;   // kv-local bound on the diagonal chunk

  int buf = 0;
  stage(0, 0);
  __syncthreads();

  for (int c = 0; c < nc; ++c) {
    if (c + 1 < nc) stage(buf ^ 1, (c + 1) * 64);  // async prefetch

    if (c <= cd) {  // uniform per-wave: skip fully-masked chunks
      // S^T = K * Q^T : C[kv][q], lane owns q = lo, kv = 16*nt + 4*lg + r
      f32x4 s[4];
      __builtin_amdgcn_s_setprio(1);
#pragma unroll
      for (int nt = 0; nt < 4; ++nt) {
        s[nt] = (f32x4){0.f, 0.f, 0.f, 0.f};
        int krow = nt * 16 + lo;
        bf16x8 kf0 = *(const bf16x8*)&Ks[buf][krow * 64 + ((lg ^ (lo & 7)) * 8)];
        bf16x8 kf1 = *(const bf16x8*)&Ks[buf][krow * 64 + (((4 + lg) ^ (lo & 7)) * 8)];
        s[nt] = __builtin_amdgcn_mfma_f32_16x16x32_bf16(kf0, qf0, s[nt], 0, 0, 0);
        s[nt] = __builtin_amdgcn_mfma_f32_16x16x32_bf16(kf1, qf1, s[nt], 0, 0, 0);
      }
      __builtin_amdgcn_s_setprio(0);

      if (c == cd) {  // causal mask, diagonal chunk only
#pragma unroll
        for (int nt = 0; nt < 4; ++nt)
#pragma unroll
          for (int r = 0; r < 4; ++r)
            s[nt][r] = (16 * nt + 4 * lg + r <= diag_rhs) ? s[nt][r] : -1e30f;
      }

      // in-lane max tree (16 values) + 2 cross-group shuffles
      float mx0 = fmaxf(fmaxf(s[0][0], s[0][1]), fmaxf(s[0][2], s[0][3]));
      float mx1 = fmaxf(fmaxf(s[1][0], s[1][1]), fmaxf(s[1][2], s[1][3]));
      float mx2 = fmaxf(fmaxf(s[2][0], s[2][1]), fmaxf(s[2][2], s[2][3]));
      float mx3 = fmaxf(fmaxf(s[3][0], s[3][1]), fmaxf(s[3][2], s[3][3]));
      float pmax = fmaxf(fmaxf(mx0, mx1), fmaxf(mx2, mx3));
      pmax = fmaxf(pmax, __shfl_xor(pmax, 16));
      pmax = fmaxf(pmax, __shfl_xor(pmax, 32));

      // defer-max rescale (threshold 40 raw = 5 nats)
      if (__any(pmax > m + 40.0f)) {
        float mn = fmaxf(m, pmax);
        float alpha = fexp2((m - mn) * C2);
        m = mn;
        lsum *= alpha;
#pragma unroll
        for (int r = 0; r < 4; ++r) {
          float ar = __shfl(alpha, (l & 48) | (4 * lg + r));
          o[0][r] *= ar; o[1][r] *= ar; o[2][r] *= ar; o[3][r] *= ar;
        }
      }

      float mC = m * C2;
      float p[4][4];
      float psum[4];
#pragma unroll
      for (int nt = 0; nt < 4; ++nt) {
        psum[nt] = 0.f;
#pragma unroll
        for (int r = 0; r < 4; ++r) {
          float e = fexp2(fmaf(s[nt][r], C2, -mC));
          p[nt][r] = e;
          psum[nt] += e;
        }
      }
      float pst = (psum[0] + psum[1]) + (psum[2] + psum[3]);
      pst += __shfl_xor(pst, 16);
      pst += __shfl_xor(pst, 32);
      lsum += pst;

      // P[q=lo][kv] -> per-wave LDS (swizzled), packed b32 writes
#pragma unroll
      for (int nt = 0; nt < 4; ++nt) {
        int chunk = (2 * nt + (lg >> 1)) ^ (lo & 7);
        int base = lo * 64 + chunk * 8 + 4 * (lg & 1);
        bf16x2 w0, w1;
        w0[0] = (bf16)p[nt][0]; w0[1] = (bf16)p[nt][1];
        w1[0] = (bf16)p[nt][2]; w1[1] = (bf16)p[nt][3];
        *(bf16x2*)&P[w][base] = w0;
        *(bf16x2*)&P[w][base + 2] = w1;
      }
      bf16x8 pf0 = *(const bf16x8*)&P[w][lo * 64 + ((lg ^ (lo & 7)) * 8)];
      bf16x8 pf1 = *(const bf16x8*)&P[w][lo * 64 + (((4 + lg) ^ (lo & 7)) * 8)];

      __builtin_amdgcn_s_setprio(1);
#pragma unroll
      for (int nt = 0; nt < 4; ++nt) {
        int vrow = nt * 16 + lo;
        bf16x8 vf0 = *(const bf16x8*)&Vs[buf][vrow * 64 + ((lg ^ (lo & 7)) * 8)];
        bf16x8 vf1 = *(const bf16x8*)&Vs[buf][vrow * 64 + (((4 + lg) ^ (lo & 7)) * 8)];
        o[nt] = __builtin_amdgcn_mfma_f32_16x16x32_bf16(pf0, vf0, o[nt], 0, 0, 0);
        o[nt] = __builtin_amdgcn_mfma_f32_16x16x32_bf16(pf1, vf1, o[nt], 0, 0, 0);
      }
      __builtin_amdgcn_s_setprio(0);
    }

    __syncthreads();  // drains prefetch + all waves done with buf
    buf ^= 1;
  }

#pragma unroll
  for (int r = 0; r < 4; ++r) {
    float ls = __shfl(lsum, (l & 48) | (4 * lg + r));
    float inv = 1.0f / ls;
    int qrow = q0 + 4 * lg + r;
#pragma unroll
    for (int nt = 0; nt < 4; ++nt)
      attn[((size_t)b * SEQ + qrow) * D_MODEL + h * HEADDIM + nt * 16 + lo] =
          (bf16)(o[nt][r] * inv);
  }
}

extern "C" void kernel_launch(void* const* d_in, const int* in_sizes, int n_in,
                              void* d_out, int out_size, void* d_ws, size_t ws_size,
                              hipStream_t stream) {
  const float* x = (const float*)d_in[0];
  const float* ln_w = (const float*)d_in[1];
  const float* ln_b = (const float*)d_in[2];
  const float* wq = (const float*)d_in[3];
  const float* wk = (const float*)d_in[4];
  const float* wv = (const float*)d_in[5];
  const float* wo = (const float*)d_in[6];
  float* out = (float*)d_out;
  char* ws = (char*)d_ws;

  bf16* y     = (bf16*)(ws);                     // 8 MB
  bf16* WqkvT = (bf16*)(ws + (8u << 20));        // 6 MB  [3072][1024]
  bf16* woT   = (bf16*)(ws + (14u << 20));       // 2 MB  [1024][1024]
  bf16* qb    = (bf16*)(ws + (16u << 20));       // 8 MB  [b][h][s][e]
  bf16* kb    = (bf16*)(ws + (24u << 20));       // 8 MB  [b][h][s][e]
  bf16* vtb   = (bf16*)(ws + (32u << 20));       // 8 MB  [b][h][e][s]
  bf16* attnb = (bf16*)(ws + (40u << 20));       // 8 MB  [b*s][h*e]

  // LayerNorm
  ln_kernel<<<NBATCH * SEQ, 256, 0, stream>>>(x, ln_w, ln_b, y);

  // weights -> k-contiguous bf16 transposes
  transpose_cast<<<dim3(16, 16), 256, 0, stream>>>(wq, WqkvT,                64, 1024, 1, 65536, 65536);
  transpose_cast<<<dim3(16, 16), 256, 0, stream>>>(wk, WqkvT + (1u << 20),   64, 1024, 1, 65536, 65536);
  transpose_cast<<<dim3(16, 16), 256, 0, stream>>>(wv, WqkvT + (2u << 20),   64, 1024, 1, 65536, 65536);
  transpose_cast<<<dim3(256, 1), 256, 0, stream>>>(wo, woT,                1024, 1024, 16, 0, 0);

  // fused QKV projection: [4096,1024] x [3072,1024]^T, 3-way output decode
  gemm_bt<0, 128><<<32 * 24, 256, 0, stream>>>(y, WqkvT, 24, qb, kb, vtb);

  // causal flash attention (512 blocks x 512 thr, XCD-grouped)
  attn_kernel<<<dim3(512), 512, 0, stream>>>(qb, kb, vtb, attnb);

  // output projection + residual: [4096,1024] x [1024,1024]^T + x, 64x128 tiles
  gemm_bt<2, 64><<<64 * 8, 256, 0, stream>>>(attnb, woT, 8, out, (void*)x, nullptr);
}